// Round 2
// baseline (1062.344 us; speedup 1.0000x reference)
//
#include <hip/hip_runtime.h>

#define ALPHA_F 32.0f
#define EPS_F 1e-8f
#define NEG_SLOPE_F 0.01f

#define D_IN 4096
#define D_OUT 4096
#define RNK 16
#define N_ROWS 16384
#define ROWS_PER_BLOCK 16
#define THREADS 256

// Tiny pre-pass: WaT[r][d] = Wa[d][r]  (16 x 4096). Writes coalesced.
__global__ __launch_bounds__(256) void transpose_wa(
    const float* __restrict__ Wa, float* __restrict__ WaT)
{
    const int idx = blockIdx.x * 256 + threadIdx.x;   // 0..65535
    const int r = idx >> 12;                          // 0..15
    const int d = idx & 4095;
    WaT[idx] = Wa[d * RNK + r];
}

// One block = 16 rows (4 waves x 4 rows/wave).
// Phase A: new_x = x @ Wa, via WaT (coalesced L2 weight loads)
// Stage 2: h_t1 = h@Wc + new_x@Wd + h; min-max over R; leaky; u = 32*(new_x+act)
// Phase B: y = u @ Wb (coalesced)
__global__ __launch_bounds__(THREADS, 4) void ssm_lora_fused(
    const float* __restrict__ x,
    const float* __restrict__ h_t,
    const float* __restrict__ WaT,
    const float* __restrict__ Wb,
    const float* __restrict__ Wc,
    const float* __restrict__ Wd,
    float* __restrict__ y)
{
    // stride 68 floats (272B): 16 writers at 272B stride -> 2-way bank alias (free)
    __shared__ float red[4][16][68];
    __shared__ float lds_nx[16][16];
    __shared__ float lds_u[16][16];

    const int tid  = threadIdx.x;
    const int lane = tid & 63;
    const int w    = tid >> 6;
    const long row0 = (long)blockIdx.x * ROWS_PER_BLOCK;
    const int wr0  = w * 4;  // wave's first local row

    // ---------------- Phase A ----------------
    float acc[4][16];
    #pragma unroll
    for (int rr = 0; rr < 4; ++rr)
        #pragma unroll
        for (int r = 0; r < 16; ++r) acc[rr][r] = 0.0f;

    const float4* x4   = (const float4*)x;
    const float4* WaT4 = (const float4*)WaT;   // [16][1024]
    const long xbase = (row0 + wr0) * (D_IN / 4);

    // prefetch k=0
    float4 xv[4];
    #pragma unroll
    for (int rr = 0; rr < 4; ++rr)
        xv[rr] = x4[xbase + (long)rr * (D_IN / 4) + lane];

    for (int k = 0; k < 16; ++k) {
        float4 xc[4];
        #pragma unroll
        for (int rr = 0; rr < 4; ++rr) xc[rr] = xv[rr];
        if (k < 15) {
            const int pn = lane + ((k + 1) << 6);
            #pragma unroll
            for (int rr = 0; rr < 4; ++rr)
                xv[rr] = x4[xbase + (long)rr * (D_IN / 4) + pn];
        }
        const int p = lane + (k << 6);
        #pragma unroll
        for (int r = 0; r < 16; ++r) {
            const float4 w4 = WaT4[(size_t)r * (D_IN / 4) + p];  // coalesced, L2-hit
            #pragma unroll
            for (int rr = 0; rr < 4; ++rr) {
                acc[rr][r] += xc[rr].x * w4.x + xc[rr].y * w4.y
                            + xc[rr].z * w4.z + xc[rr].w * w4.w;
            }
        }
    }

    // partial cross-lane reduce: lanes {4i..4i+3} -> lane 4i holds 4-lane sum
    #pragma unroll
    for (int rr = 0; rr < 4; ++rr)
        #pragma unroll
        for (int r = 0; r < 16; ++r) {
            float v = acc[rr][r];
            v += __shfl_xor(v, 1, 64);
            v += __shfl_xor(v, 2, 64);
            acc[rr][r] = v;
        }
    if ((lane & 3) == 0) {
        const int li = lane >> 2;  // 0..15 partial index
        #pragma unroll
        for (int rr = 0; rr < 4; ++rr)
            #pragma unroll
            for (int r = 0; r < 16; ++r)
                red[w][li][rr * 16 + r] = acc[rr][r];
    }
    __syncthreads();

    // ---------------- Stage 2 (thread t = (row = t>>4, r = t&15)) ----------
    {
        const int row  = tid >> 4;
        const int r    = tid & 15;
        const int w2   = tid >> 6;
        const int slot = tid & 63;
        float s = 0.0f;
        #pragma unroll
        for (int i = 0; i < 16; ++i) s += red[w2][i][slot];
        lds_nx[row][r] = s;
        __syncthreads();

        const float* hrow = h_t + (row0 + row) * RNK;
        float h1 = hrow[r];  // the "+ h_t" term
        #pragma unroll
        for (int j = 0; j < 16; ++j)
            h1 += hrow[j] * Wc[j * 16 + r] + lds_nx[row][j] * Wd[j * 16 + r];

        // min/max over the 16 threads of this row (xor masks < 16 stay in-group)
        float mn = h1, mx = h1;
        #pragma unroll
        for (int m = 1; m <= 8; m <<= 1) {
            mn = fminf(mn, __shfl_xor(mn, m, 64));
            mx = fmaxf(mx, __shfl_xor(mx, m, 64));
        }
        const float hn = (h1 - mn) / (mx - mn + EPS_F);
        const float a  = (hn >= 0.0f) ? hn : NEG_SLOPE_F * hn;
        lds_u[row][r] = ALPHA_F * (s + a);   // fold ALPHA here
    }
    __syncthreads();

    // ---------------- Phase B ----------------
    float4 uu[4][4];
    #pragma unroll
    for (int rr = 0; rr < 4; ++rr)
        #pragma unroll
        for (int j = 0; j < 4; ++j)
            uu[rr][j] = ((const float4*)lds_u[wr0 + rr])[j];

    const float4* Wb4 = (const float4*)Wb;    // [16][1024] float4
    float4* y4 = (float4*)y;
    const long ybase = (row0 + wr0) * (D_OUT / 4);

    for (int k = 0; k < 16; ++k) {
        const int p = lane + (k << 6);
        float4 o[4];
        #pragma unroll
        for (int rr = 0; rr < 4; ++rr) { o[rr].x = o[rr].y = o[rr].z = o[rr].w = 0.0f; }
        // two batches of 8 Wb rows to keep VGPR pressure <= 128
        #pragma unroll
        for (int half = 0; half < 2; ++half) {
            float4 wb[8];
            #pragma unroll
            for (int j = 0; j < 8; ++j)
                wb[j] = Wb4[(size_t)(half * 8 + j) * (D_OUT / 4) + p];
            #pragma unroll
            for (int rr = 0; rr < 4; ++rr) {
                #pragma unroll
                for (int j = 0; j < 8; ++j) {
                    const int r2 = half * 8 + j;
                    const float us = ((const float*)&uu[rr][0])[r2];
                    o[rr].x += us * wb[j].x;
                    o[rr].y += us * wb[j].y;
                    o[rr].z += us * wb[j].z;
                    o[rr].w += us * wb[j].w;
                }
            }
        }
        #pragma unroll
        for (int rr = 0; rr < 4; ++rr)
            y4[ybase + (long)rr * (D_OUT / 4) + p] = o[rr];
    }
}

extern "C" void kernel_launch(void* const* d_in, const int* in_sizes, int n_in,
                              void* d_out, int out_size, void* d_ws, size_t ws_size,
                              hipStream_t stream) {
    const float* x   = (const float*)d_in[0];
    const float* h_t = (const float*)d_in[1];
    const float* Wa  = (const float*)d_in[2];
    const float* Wb  = (const float*)d_in[3];
    const float* Wc  = (const float*)d_in[4];
    const float* Wd  = (const float*)d_in[5];
    float* y   = (float*)d_out;
    float* WaT = (float*)d_ws;   // 16*4096 floats = 256 KiB

    transpose_wa<<<dim3((D_IN * RNK) / 256), dim3(256), 0, stream>>>(Wa, WaT);
    ssm_lora_fused<<<dim3(N_ROWS / ROWS_PER_BLOCK), dim3(THREADS), 0, stream>>>(
        x, h_t, WaT, Wb, Wc, Wd, y);
}